// Round 1
// baseline (171.669 us; speedup 1.0000x reference)
//
#include <hip/hip_runtime.h>

#define NBINS 10
#define ACC_STRIDE 16   // floats per accumulator line (64 B padding vs atomic contention)

// ws layout (bytes):
//   [0, 640)    : 10 bin counters, one uint per 64B line  (u32 at float-index b*ACC_STRIDE)
//   [640, 644)  : wsum (float)
//   [1024, ...) : finalized params: beta[0..9], total_num at [10]
#define WSUM_OFF   (NBINS * ACC_STRIDE)   // float index 160
#define PARAMS_OFF 256                    // float index of finalized params

__device__ __forceinline__ int bin_of(float g) {
    // digitize(g, edges)-1 with edges[k]=k/10 (fp32), g in [0,1)
    int b = 0;
    b += g >= 0.1f; b += g >= 0.2f; b += g >= 0.3f;
    b += g >= 0.4f; b += g >= 0.5f; b += g >= 0.6f;
    b += g >= 0.7f; b += g >= 0.8f; b += g >= 0.9f;
    return b;
}

__device__ __forceinline__ void hist_elem(float a, float b, float w,
                                          float& wsum, int* cnt) {
    float d = b - a;
    float denom = sqrtf(d * d + 0.0004f);   // MIU*MIU evaluated as double->fp32(4e-4)
    float g = fabsf(d / denom);
    wsum += w;                              // total_num sums ALL weights
    bool valid = w > 0.0f;
    int bin = bin_of(g);
#pragma unroll
    for (int k = 0; k < NBINS; ++k)
        cnt[k] += (valid && bin == k) ? 1 : 0;
}

__global__ __launch_bounds__(256) void ghmr_hist(
    const float* __restrict__ dt, const float* __restrict__ dl,
    const float* __restrict__ dw, int n,
    unsigned int* __restrict__ counts_acc, float* __restrict__ wsum_acc)
{
    const int tid = blockIdx.x * blockDim.x + threadIdx.x;
    const int nthreads = gridDim.x * blockDim.x;
    const int n4 = n >> 2;

    const float4* dt4 = (const float4*)dt;
    const float4* dl4 = (const float4*)dl;
    const float4* dw4 = (const float4*)dw;

    float wsum = 0.0f;
    int cnt[NBINS];
#pragma unroll
    for (int k = 0; k < NBINS; ++k) cnt[k] = 0;

    for (int i = tid; i < n4; i += nthreads) {
        float4 a = dt4[i];
        float4 b = dl4[i];
        float4 w = dw4[i];
        hist_elem(a.x, b.x, w.x, wsum, cnt);
        hist_elem(a.y, b.y, w.y, wsum, cnt);
        hist_elem(a.z, b.z, w.z, wsum, cnt);
        hist_elem(a.w, b.w, w.w, wsum, cnt);
    }
    // scalar tail
    for (int i = (n4 << 2) + tid; i < n; i += nthreads)
        hist_elem(dt[i], dl[i], dw[i], wsum, cnt);

    // wave-level butterfly reduce (wave = 64 lanes)
#pragma unroll
    for (int off = 32; off > 0; off >>= 1) {
        wsum += __shfl_down(wsum, off);
#pragma unroll
        for (int k = 0; k < NBINS; ++k) cnt[k] += __shfl_down(cnt[k], off);
    }

    __shared__ float s_w[4];
    __shared__ int   s_c[4][NBINS];
    const int lane = threadIdx.x & 63;
    const int wave = threadIdx.x >> 6;
    if (lane == 0) {
        s_w[wave] = wsum;
#pragma unroll
        for (int k = 0; k < NBINS; ++k) s_c[wave][k] = cnt[k];
    }
    __syncthreads();
    if (threadIdx.x == 0)
        atomicAdd(wsum_acc, s_w[0] + s_w[1] + s_w[2] + s_w[3]);
    if (threadIdx.x < NBINS) {
        int tc = s_c[0][threadIdx.x] + s_c[1][threadIdx.x] +
                 s_c[2][threadIdx.x] + s_c[3][threadIdx.x];
        atomicAdd(&counts_acc[threadIdx.x * ACC_STRIDE], (unsigned int)tc);
    }
}

__global__ void ghmr_finalize(const unsigned int* __restrict__ counts_acc,
                              const float* __restrict__ wsum_acc,
                              float* __restrict__ params)
{
    if (threadIdx.x == 0) {
        float total = fmaxf(wsum_acc[0], 1.0f);
        float cf[NBINS];
        int nne = 0;
#pragma unroll
        for (int b = 0; b < NBINS; ++b) {
            cf[b] = (float)counts_acc[b * ACC_STRIDE];
            nne += (cf[b] > 0.0f) ? 1 : 0;
        }
        float nnef = fmaxf((float)nne, 1.0f);
#pragma unroll
        for (int b = 0; b < NBINS; ++b) {
            float pbw = (cf[b] > 0.0f) ? (total / fmaxf(cf[b], 1.0f)) : 0.0f;
            params[b] = pbw / nnef;   // beta per bin (already / n_nonempty)
        }
        params[NBINS] = total;
    }
}

__device__ __forceinline__ float apply_elem(float a, float b, float w,
                                            const float* sb, float total) {
    float d = b - a;
    float denom = sqrtf(d * d + 0.0004f);
    float g = fabsf(d / denom);
    float asl1 = denom - 0.02f;
    float r = 0.0f;
    if (w > 0.0f) r = asl1 * sb[bin_of(g)] / total;
    return r;
}

__global__ __launch_bounds__(256) void ghmr_apply(
    const float* __restrict__ dt, const float* __restrict__ dl,
    const float* __restrict__ dw, const float* __restrict__ params,
    float* __restrict__ out, int n)
{
    __shared__ float sb[NBINS + 1];
    if (threadIdx.x <= NBINS) sb[threadIdx.x] = params[threadIdx.x];
    __syncthreads();
    const float total = sb[NBINS];

    const int tid = blockIdx.x * blockDim.x + threadIdx.x;
    const int nthreads = gridDim.x * blockDim.x;
    const int n4 = n >> 2;

    const float4* dt4 = (const float4*)dt;
    const float4* dl4 = (const float4*)dl;
    const float4* dw4 = (const float4*)dw;
    float4* out4 = (float4*)out;

    for (int i = tid; i < n4; i += nthreads) {
        float4 a = dt4[i];
        float4 b = dl4[i];
        float4 w = dw4[i];
        float4 r;
        r.x = apply_elem(a.x, b.x, w.x, sb, total);
        r.y = apply_elem(a.y, b.y, w.y, sb, total);
        r.z = apply_elem(a.z, b.z, w.z, sb, total);
        r.w = apply_elem(a.w, b.w, w.w, sb, total);
        out4[i] = r;
    }
    for (int i = (n4 << 2) + tid; i < n; i += nthreads)
        out[i] = apply_elem(dt[i], dl[i], dw[i], sb, total);
}

extern "C" void kernel_launch(void* const* d_in, const int* in_sizes, int n_in,
                              void* d_out, int out_size, void* d_ws, size_t ws_size,
                              hipStream_t stream) {
    const float* dt = (const float*)d_in[0];   // delta_targets
    const float* dl = (const float*)d_in[1];   // deltas
    const float* dw = (const float*)d_in[2];   // delta_weights
    float* out = (float*)d_out;
    const int n = in_sizes[0];

    float* ws_f = (float*)d_ws;
    unsigned int* counts_acc = (unsigned int*)d_ws;
    float* wsum_acc = ws_f + WSUM_OFF;
    float* params = ws_f + PARAMS_OFF;

    // zero the accumulators (ws is poisoned 0xAA before every launch)
    hipMemsetAsync(d_ws, 0, 1024, stream);

    int n4 = n >> 2;
    int blocks = (n4 + 255) / 256;
    if (blocks > 2048) blocks = 2048;
    if (blocks < 1) blocks = 1;

    ghmr_hist<<<blocks, 256, 0, stream>>>(dt, dl, dw, n, counts_acc, wsum_acc);
    ghmr_finalize<<<1, 64, 0, stream>>>(counts_acc, wsum_acc, params);
    ghmr_apply<<<blocks, 256, 0, stream>>>(dt, dl, dw, params, out, n);
}

// Round 2
// 145.198 us; speedup vs baseline: 1.1823x; 1.1823x over previous
//
#include <hip/hip_runtime.h>

#define NBINS 10
#define PROW 16          // floats per per-block partial row (64 B)
#define MAXBLOCKS 4096

// ws layout (floats):
//   [0, nblocks*PROW)      : per-block partials: [wsum, cnt0..cnt9, pad...]
//   [MAXBLOCKS*PROW, +16)  : finalized params: sb[0..9] = beta_b/total, [10] unused
#define PARAMS_OFF (MAXBLOCKS * PROW)

__device__ __forceinline__ int bin_of(float g) {
    // digitize(g, edges)-1 with edges[k]=k/10 (fp32), g in [0,1)
    int b = 0;
    b += g >= 0.1f; b += g >= 0.2f; b += g >= 0.3f;
    b += g >= 0.4f; b += g >= 0.5f; b += g >= 0.6f;
    b += g >= 0.7f; b += g >= 0.8f; b += g >= 0.9f;
    return b;
}

__device__ __forceinline__ void hist_elem(float a, float b, float w,
                                          float& wsum, int* cnt) {
    float d = b - a;
    float denom = sqrtf(d * d + 0.0004f);   // MIU*MIU as double->fp32
    float g = fabsf(d / denom);
    wsum += w;                              // total_num sums ALL weights
    bool valid = w > 0.0f;
    int bin = bin_of(g);
#pragma unroll
    for (int k = 0; k < NBINS; ++k)
        cnt[k] += (valid && bin == k) ? 1 : 0;
}

__global__ __launch_bounds__(256) void ghmr_hist(
    const float* __restrict__ dt, const float* __restrict__ dl,
    const float* __restrict__ dw, int n, float* __restrict__ partials)
{
    const int tid = blockIdx.x * blockDim.x + threadIdx.x;
    const int nthreads = gridDim.x * blockDim.x;
    const int n4 = n >> 2;

    const float4* dt4 = (const float4*)dt;
    const float4* dl4 = (const float4*)dl;
    const float4* dw4 = (const float4*)dw;

    float wsum = 0.0f;
    int cnt[NBINS];
#pragma unroll
    for (int k = 0; k < NBINS; ++k) cnt[k] = 0;

    for (int i = tid; i < n4; i += nthreads) {
        float4 a = dt4[i];
        float4 b = dl4[i];
        float4 w = dw4[i];
        hist_elem(a.x, b.x, w.x, wsum, cnt);
        hist_elem(a.y, b.y, w.y, wsum, cnt);
        hist_elem(a.z, b.z, w.z, wsum, cnt);
        hist_elem(a.w, b.w, w.w, wsum, cnt);
    }
    for (int i = (n4 << 2) + tid; i < n; i += nthreads)
        hist_elem(dt[i], dl[i], dw[i], wsum, cnt);

    // wave butterfly reduce (64 lanes)
#pragma unroll
    for (int off = 32; off > 0; off >>= 1) {
        wsum += __shfl_down(wsum, off);
#pragma unroll
        for (int k = 0; k < NBINS; ++k) cnt[k] += __shfl_down(cnt[k], off);
    }

    __shared__ float s_w[4];
    __shared__ int   s_c[4][NBINS];
    const int lane = threadIdx.x & 63;
    const int wave = threadIdx.x >> 6;
    if (lane == 0) {
        s_w[wave] = wsum;
#pragma unroll
        for (int k = 0; k < NBINS; ++k) s_c[wave][k] = cnt[k];
    }
    __syncthreads();
    // one 64B row per block; no atomics anywhere
    if (threadIdx.x == 0)
        partials[blockIdx.x * PROW] = s_w[0] + s_w[1] + s_w[2] + s_w[3];
    if (threadIdx.x < NBINS) {
        int tc = s_c[0][threadIdx.x] + s_c[1][threadIdx.x] +
                 s_c[2][threadIdx.x] + s_c[3][threadIdx.x];
        partials[blockIdx.x * PROW + 1 + threadIdx.x] = (float)tc;
    }
}

__global__ __launch_bounds__(256) void ghmr_finalize(
    const float* __restrict__ partials, int nblocks, float* __restrict__ params)
{
    // 256 threads: thread t sums rows t, t+256, ...
    float acc[NBINS + 1];
#pragma unroll
    for (int k = 0; k <= NBINS; ++k) acc[k] = 0.0f;
    for (int r = threadIdx.x; r < nblocks; r += 256) {
        const float* row = partials + r * PROW;
#pragma unroll
        for (int k = 0; k <= NBINS; ++k) acc[k] += row[k];
    }
#pragma unroll
    for (int off = 32; off > 0; off >>= 1)
#pragma unroll
        for (int k = 0; k <= NBINS; ++k) acc[k] += __shfl_down(acc[k], off);

    __shared__ float s_acc[4][NBINS + 1];
    const int lane = threadIdx.x & 63;
    const int wave = threadIdx.x >> 6;
    if (lane == 0)
#pragma unroll
        for (int k = 0; k <= NBINS; ++k) s_acc[wave][k] = acc[k];
    __syncthreads();

    if (threadIdx.x == 0) {
        float total = fmaxf(s_acc[0][0] + s_acc[1][0] + s_acc[2][0] + s_acc[3][0], 1.0f);
        float cf[NBINS];
        int nne = 0;
#pragma unroll
        for (int b = 0; b < NBINS; ++b) {
            cf[b] = s_acc[0][b + 1] + s_acc[1][b + 1] + s_acc[2][b + 1] + s_acc[3][b + 1];
            nne += (cf[b] > 0.0f) ? 1 : 0;
        }
        float nnef = fmaxf((float)nne, 1.0f);
#pragma unroll
        for (int b = 0; b < NBINS; ++b) {
            // beta_b / n_nonempty / total, pre-folded: apply is a single multiply
            float pbw = (cf[b] > 0.0f) ? (total / fmaxf(cf[b], 1.0f)) : 0.0f;
            params[b] = pbw / nnef / total;
        }
    }
}

__device__ __forceinline__ float apply_elem(float a, float b, float w,
                                            const float* sb) {
    float d = b - a;
    float denom = sqrtf(d * d + 0.0004f);
    float g = fabsf(d / denom);
    float asl1 = denom - 0.02f;
    float r = 0.0f;
    if (w > 0.0f) r = asl1 * sb[bin_of(g)];
    return r;
}

__global__ __launch_bounds__(256) void ghmr_apply(
    const float* __restrict__ dt, const float* __restrict__ dl,
    const float* __restrict__ dw, const float* __restrict__ params,
    float* __restrict__ out, int n)
{
    __shared__ float sb[NBINS];
    if (threadIdx.x < NBINS) sb[threadIdx.x] = params[threadIdx.x];
    __syncthreads();

    const int tid = blockIdx.x * blockDim.x + threadIdx.x;
    const int nthreads = gridDim.x * blockDim.x;
    const int n4 = n >> 2;

    const float4* dt4 = (const float4*)dt;
    const float4* dl4 = (const float4*)dl;
    const float4* dw4 = (const float4*)dw;
    float4* out4 = (float4*)out;

    for (int i = tid; i < n4; i += nthreads) {
        float4 a = dt4[i];
        float4 b = dl4[i];
        float4 w = dw4[i];
        float4 r;
        r.x = apply_elem(a.x, b.x, w.x, sb);
        r.y = apply_elem(a.y, b.y, w.y, sb);
        r.z = apply_elem(a.z, b.z, w.z, sb);
        r.w = apply_elem(a.w, b.w, w.w, sb);
        out4[i] = r;
    }
    for (int i = (n4 << 2) + tid; i < n; i += nthreads)
        out[i] = apply_elem(dt[i], dl[i], dw[i], sb);
}

extern "C" void kernel_launch(void* const* d_in, const int* in_sizes, int n_in,
                              void* d_out, int out_size, void* d_ws, size_t ws_size,
                              hipStream_t stream) {
    const float* dt = (const float*)d_in[0];   // delta_targets
    const float* dl = (const float*)d_in[1];   // deltas
    const float* dw = (const float*)d_in[2];   // delta_weights
    float* out = (float*)d_out;
    const int n = in_sizes[0];

    float* ws_f = (float*)d_ws;
    float* partials = ws_f;
    float* params = ws_f + PARAMS_OFF;

    int n4 = n >> 2;
    int blocks = (n4 + 255) / 256;
    if (blocks > 2048) blocks = 2048;
    if (blocks < 1) blocks = 1;

    ghmr_hist<<<blocks, 256, 0, stream>>>(dt, dl, dw, n, partials);
    ghmr_finalize<<<1, 256, 0, stream>>>(partials, blocks, params);
    ghmr_apply<<<blocks, 256, 0, stream>>>(dt, dl, dw, params, out, n);
}